// Round 7
// baseline (213.207 us; speedup 1.0000x reference)
//
#include <hip/hip_runtime.h>
#include <hip/hip_bf16.h>

typedef __attribute__((ext_vector_type(8))) short bfrag;   // 8 bf16 (A/B operand)
typedef __attribute__((ext_vector_type(4))) float facc;    // 4 f32  (C/D operand)
typedef __attribute__((ext_vector_type(2))) float f32x2;

static __device__ __forceinline__ float bf2f_lo(unsigned int u) {
    return __uint_as_float(u << 16);
}
static __device__ __forceinline__ float bf2f_hi(unsigned int u) {
    return __uint_as_float(u & 0xffff0000u);
}
static __device__ __forceinline__ unsigned short f2bf(float f) {
    __hip_bfloat16 b = __float2bfloat16(f);  // RNE
    return *reinterpret_cast<unsigned short*>(&b);
}

// ---------------------------------------------------------------------------
// Merged precompute: Y[row][0:128] = h@W1[0:128], Y[row][128:256] = h@W1[128:256]
// for BOTH node tables, output in OCP fp8-e4m3 (gather table 38 MB).
// MFMA 16x16x32 bf16; wave w owns cols [w*64, w*64+64); W1 frags in registers.
// D layout (verified): col = lane&15, row = (lane>>4)*4 + reg.
// ---------------------------------------------------------------------------
extern "C" __global__ __launch_bounds__(256)
void precompute_mfma(const float* __restrict__ hu, int nu,
                     const float* __restrict__ hi, int ni,
                     const float* __restrict__ W1,
                     unsigned char* __restrict__ Yu,
                     unsigned char* __restrict__ Yi)
{
    const int tid = threadIdx.x, wave = tid >> 6, lane = tid & 63;
    const int g = lane >> 4, e16 = lane & 15;
    const int c0 = wave * 64;

    bfrag bfr[4][4];
    #pragma unroll
    for (int nt = 0; nt < 4; ++nt) {
        const int j = c0 + nt * 16 + e16;
        #pragma unroll
        for (int kk = 0; kk < 4; ++kk) {
            bfrag v;
            #pragma unroll
            for (int i = 0; i < 8; ++i) {
                int k = kk * 32 + g * 8 + i;
                float w = (j < 128) ? W1[(size_t)k * 128 + j]
                                    : W1[(size_t)(128 + k) * 128 + (j - 128)];
                v[i] = (short)f2bf(w);
            }
            bfr[nt][kk] = v;
        }
    }

    const int tu = (nu + 15) >> 4, ti = (ni + 15) >> 4, tt = tu + ti;
    for (int tile = blockIdx.x; tile < tt; tile += gridDim.x) {
        const float* h; unsigned char* Y; int n, node0;
        if (tile < tu) { h = hu; Y = Yu; n = nu; node0 = tile * 16; }
        else           { h = hi; Y = Yi; n = ni; node0 = (tile - tu) * 16; }

        int arow = node0 + e16; if (arow >= n) arow = n - 1;
        facc acc[4] = {{0,0,0,0},{0,0,0,0},{0,0,0,0},{0,0,0,0}};
        #pragma unroll
        for (int kk = 0; kk < 4; ++kk) {
            const float* ap = h + (size_t)arow * 128 + kk * 32 + g * 8;
            float4 a0 = *(const float4*)ap;
            float4 a1v = *(const float4*)(ap + 4);
            bfrag af;
            af[0] = (short)f2bf(a0.x);  af[1] = (short)f2bf(a0.y);
            af[2] = (short)f2bf(a0.z);  af[3] = (short)f2bf(a0.w);
            af[4] = (short)f2bf(a1v.x); af[5] = (short)f2bf(a1v.y);
            af[6] = (short)f2bf(a1v.z); af[7] = (short)f2bf(a1v.w);
            #pragma unroll
            for (int nt = 0; nt < 4; ++nt)
                acc[nt] = __builtin_amdgcn_mfma_f32_16x16x32_bf16(af, bfr[nt][kk], acc[nt], 0, 0, 0);
        }
        #pragma unroll
        for (int nt = 0; nt < 4; ++nt) {
            unsigned int pk = __builtin_amdgcn_cvt_pk_fp8_f32(acc[nt][0], acc[nt][1], 0u, false);
            pk = __builtin_amdgcn_cvt_pk_fp8_f32(acc[nt][2], acc[nt][3], pk, true);
            #pragma unroll
            for (int r = 0; r < 4; ++r) {
                int row = node0 + g * 4 + r;
                if (row < n)
                    Y[(size_t)row * 256 + c0 + nt * 16 + e16] =
                        (unsigned char)(pk >> (8 * r));
            }
        }
    }
}

// ---------------------------------------------------------------------------
// Edge phase: 16 edges/wave/iter, edges-as-columns MFMA, software-pipelined.
// Round-7: full-line quad gathers — lane l serves edge l>>2, slot l&3; each
// gather instruction reads 16 complete 64B lines (was 16 scattered 32B
// requests): Y requests/batch 128 -> 64. Gathered quads bounce through a
// per-wave LDS stage (16B-granule XOR swizzle by edge) into MFMA layout.
// Prefetch state in NAMED uint4 registers (no arrays -> no scratch).
// ---------------------------------------------------------------------------
extern "C" __global__ __launch_bounds__(256, 3)
void edge_mfma(const unsigned char* __restrict__ Yu,
               const unsigned char* __restrict__ Yi,
               const float* __restrict__ ef_orders,
               const float* __restrict__ ef_rev,
               const int* __restrict__ src_orders,
               const int* __restrict__ dst_orders,
               const int* __restrict__ src_rev,
               const int* __restrict__ dst_rev,
               const float* __restrict__ W1,
               const float* __restrict__ b1,
               const float* __restrict__ W2,
               const float* __restrict__ b2,
               const float* __restrict__ W3,
               const float* __restrict__ b3,
               float* __restrict__ out, int E)
{
    __shared__ __align__(16) unsigned short d1_lds[4][16][128];      // 16 KB
    __shared__ __align__(16) unsigned char  ystage[4][2][16][128];   // 16 KB
    const int tid = threadIdx.x, wave = tid >> 6, lane = tid & 63;
    const int g = lane >> 4, e16 = lane & 15;
    const int eq = lane >> 2, sq = lane & 3;       // quad mapping for gathers
    unsigned short (*my_lds)[128] = d1_lds[wave];
    unsigned char (*ys_l)[128] = ystage[wave][0];
    unsigned char (*yd_l)[128] = ystage[wave][1];
    const int swzb = (e16 & 7) << 3;   // D1 buffer: bf16-unit XOR, 16B granule

    // A frags for ef GEMM: W1c^T tiles; K-slot 16 carries b1 (B supplies 1.0)
    bfrag a1[8];
    #pragma unroll
    for (int t = 0; t < 8; ++t) {
        bfrag v;
        #pragma unroll
        for (int i = 0; i < 8; ++i) {
            const int k = g * 8 + i;
            unsigned short s16 = 0;
            if (k < 16)       s16 = f2bf(W1[(size_t)(256 + k) * 128 + t * 16 + e16]);
            else if (k == 16) s16 = f2bf(b1[t * 16 + e16]);
            v[i] = (short)s16;
        }
        a1[t] = v;
    }
    // W2^T A-frags for the second GEMM
    bfrag w2t[2][4];
    #pragma unroll
    for (int nt = 0; nt < 2; ++nt)
        #pragma unroll
        for (int kk = 0; kk < 4; ++kk) {
            bfrag v;
            #pragma unroll
            for (int i = 0; i < 8; ++i) {
                int k = kk * 32 + g * 8 + i;
                v[i] = (short)f2bf(W2[(size_t)k * 32 + nt * 16 + e16]);
            }
            w2t[nt][kk] = v;
        }
    float b2v[2][4], w3v[2][4];
    #pragma unroll
    for (int nt = 0; nt < 2; ++nt)
        #pragma unroll
        for (int r = 0; r < 4; ++r) {
            b2v[nt][r] = b2[nt * 16 + g * 4 + r];
            w3v[nt][r] = W3[nt * 16 + g * 4 + r];
        }
    const float b3s = b3[0];

    const long twoE = 2L * E;
    const int nbatch = (int)((twoE + 15) >> 4);
    const int stride = gridDim.x * 4;
    int b = blockIdx.x * 4 + wave;

    // pipeline state — all named scalars/vectors (register-resident)
    int s_pf = 0, d_pf = 0;
    uint4 ysA, ysB, ydA, ydB;
    float4 ef0 = make_float4(0, 0, 0, 0), ef1 = make_float4(0, 0, 0, 0);

#define LOADIDX(BB) do {                                                      \
        long el_ = ((long)(BB) << 4) + eq;                                    \
        if (el_ >= twoE) el_ = twoE - 1;                                      \
        const bool rv_ = el_ >= E;                                            \
        const int ee_ = (int)(rv_ ? el_ - E : el_);                           \
        s_pf = (rv_ ? src_rev : src_orders)[ee_];                             \
        d_pf = (rv_ ? dst_rev : dst_orders)[ee_];                             \
    } while (0)

#define GATHER(BB) do {                                                       \
        long elq_ = ((long)(BB) << 4) + eq;                                   \
        if (elq_ >= twoE) elq_ = twoE - 1;                                    \
        const bool rvq_ = elq_ >= E;                                          \
        const unsigned char* ps_ = (rvq_ ? Yi : Yu) + (size_t)s_pf * 256 + sq * 16; \
        const unsigned char* pd_ = (rvq_ ? Yu : Yi) + (size_t)d_pf * 256 + 128 + sq * 16; \
        ysA = *(const uint4*)(ps_);       ysB = *(const uint4*)(ps_ + 64);    \
        ydA = *(const uint4*)(pd_);       ydB = *(const uint4*)(pd_ + 64);    \
        if (g < 2) {                                                          \
            long elf_ = ((long)(BB) << 4) + e16;                              \
            if (elf_ >= twoE) elf_ = twoE - 1;                                \
            const bool rvf_ = elf_ >= E;                                      \
            const int eef_ = (int)(rvf_ ? elf_ - E : elf_);                   \
            const float* ep_ = (rvf_ ? ef_rev : ef_orders) + (size_t)eef_ * 16 + g * 8; \
            ef0 = *(const float4*)ep_;  ef1 = *(const float4*)(ep_ + 4);      \
        }                                                                     \
    } while (0)

    // regs -> LDS stage (16B granule q XOR edge&7; bijective within each row)
#define WRITESTAGE() do {                                                     \
        const int qa_ = (sq ^ (eq & 7)) << 4;                                 \
        const int qb_ = ((sq + 4) ^ (eq & 7)) << 4;                           \
        *(uint4*)&ys_l[eq][qa_] = ysA;                                        \
        *(uint4*)&ys_l[eq][qb_] = ysB;                                        \
        *(uint4*)&yd_l[eq][qa_] = ydA;                                        \
        *(uint4*)&yd_l[eq][qb_] = ydB;                                        \
    } while (0)

#define PSTEP(KK) do {                                                        \
        const int qp_ = ((((KK) * 2 + (g >> 1)) ^ (e16 & 7)) << 4) + (g & 1) * 8; \
        const uint2 YSU = *(const uint2*)&ys_l[e16][qp_];                     \
        const uint2 YDU = *(const uint2*)&yd_l[e16][qp_];                     \
        uint4 wv = *(const uint4*)&my_lds[e16][((KK) * 32 + g * 8) ^ swzb];   \
        f32x2 s01 = __builtin_amdgcn_cvt_pk_f32_fp8(YSU.x, false);            \
        f32x2 s23 = __builtin_amdgcn_cvt_pk_f32_fp8(YSU.x, true);             \
        f32x2 s45 = __builtin_amdgcn_cvt_pk_f32_fp8(YSU.y, false);            \
        f32x2 s67 = __builtin_amdgcn_cvt_pk_f32_fp8(YSU.y, true);             \
        f32x2 d01 = __builtin_amdgcn_cvt_pk_f32_fp8(YDU.x, false);            \
        f32x2 d23 = __builtin_amdgcn_cvt_pk_f32_fp8(YDU.x, true);             \
        f32x2 d45 = __builtin_amdgcn_cvt_pk_f32_fp8(YDU.y, false);            \
        f32x2 d67 = __builtin_amdgcn_cvt_pk_f32_fp8(YDU.y, true);             \
        float p0 = s01[0] + d01[0] + bf2f_lo(wv.x);                           \
        float p1 = s01[1] + d01[1] + bf2f_hi(wv.x);                           \
        float p2 = s23[0] + d23[0] + bf2f_lo(wv.y);                           \
        float p3 = s23[1] + d23[1] + bf2f_hi(wv.y);                           \
        float p4 = s45[0] + d45[0] + bf2f_lo(wv.z);                           \
        float p5 = s45[1] + d45[1] + bf2f_hi(wv.z);                           \
        float p6 = s67[0] + d67[0] + bf2f_lo(wv.w);                           \
        float p7 = s67[1] + d67[1] + bf2f_hi(wv.w);                           \
        bfrag pa;                                                             \
        pa[0] = (short)f2bf(fmaxf(p0, 0.f)); pa[1] = (short)f2bf(fmaxf(p1, 0.f)); \
        pa[2] = (short)f2bf(fmaxf(p2, 0.f)); pa[3] = (short)f2bf(fmaxf(p3, 0.f)); \
        pa[4] = (short)f2bf(fmaxf(p4, 0.f)); pa[5] = (short)f2bf(fmaxf(p5, 0.f)); \
        pa[6] = (short)f2bf(fmaxf(p6, 0.f)); pa[7] = (short)f2bf(fmaxf(p7, 0.f)); \
        acc2a = __builtin_amdgcn_mfma_f32_16x16x32_bf16(w2t[0][KK], pa, acc2a, 0, 0, 0); \
        acc2b = __builtin_amdgcn_mfma_f32_16x16x32_bf16(w2t[1][KK], pa, acc2b, 0, 0, 0); \
    } while (0)

    if (b < nbatch) {
        LOADIDX(b);
        GATHER(b);
        WRITESTAGE();
        if (b + stride < nbatch) LOADIDX(b + stride);
    }

    for (; b < nbatch; b += stride) {
        // B frag from prefetched ef (lanes g<2); bias-one at K=16 (g==2)
        bfrag eb;
        #pragma unroll
        for (int i = 0; i < 8; ++i) eb[i] = 0;
        if (g < 2) {
            eb[0] = (short)f2bf(ef0.x); eb[1] = (short)f2bf(ef0.y);
            eb[2] = (short)f2bf(ef0.z); eb[3] = (short)f2bf(ef0.w);
            eb[4] = (short)f2bf(ef1.x); eb[5] = (short)f2bf(ef1.y);
            eb[6] = (short)f2bf(ef1.z); eb[7] = (short)f2bf(ef1.w);
        } else if (g == 2) {
            eb[0] = (short)0x3F80;  // bf16 1.0 -> adds b1[n] to every column
        }

        // D1 = W1c^T @ ef^T + b1 -> bf16 LDS transpose (swizzled)
        #pragma unroll
        for (int t = 0; t < 8; ++t) {
            facc zero = {0, 0, 0, 0};
            facc d1 = __builtin_amdgcn_mfma_f32_16x16x32_bf16(a1[t], eb, zero, 0, 0, 0);
            ushort4 u;
            u.x = f2bf(d1[0]); u.y = f2bf(d1[1]); u.z = f2bf(d1[2]); u.w = f2bf(d1[3]);
            *(ushort4*)&my_lds[e16][(t * 16 + g * 4) ^ swzb] = u;
        }

        // issue next batch's gathers into regs (latency covered by PSTEP+tail)
        const int bn = b + stride;
        if (bn < nbatch) GATHER(bn);

        // P build + second GEMM (reads batch b from the LDS stage)
        facc acc2a = {0, 0, 0, 0}, acc2b = {0, 0, 0, 0};
        PSTEP(0);
        PSTEP(1);
        PSTEP(2);
        PSTEP(3);

        // tail: relu(h2+b2) . W3, reduce over g-groups, sigmoid, store
        float h3 = 0.f;
        #pragma unroll
        for (int r = 0; r < 4; ++r) {
            float h2 = fmaxf(acc2a[r] + b2v[0][r], 0.f);
            h3 = fmaf(h2, w3v[0][r], h3);
        }
        #pragma unroll
        for (int r = 0; r < 4; ++r) {
            float h2 = fmaxf(acc2b[r] + b2v[1][r], 0.f);
            h3 = fmaf(h2, w3v[1][r], h3);
        }
        h3 += __shfl_xor(h3, 16, 64);
        h3 += __shfl_xor(h3, 32, 64);
        const long el = ((long)b << 4) + lane;
        if (lane < 16 && el < twoE)
            out[el] = 1.f / (1.f + __expf(-(h3 + b3s)));

        // stage batch b+1 into LDS (vmcnt wait here, covered by PSTEP+tail)
        if (bn < nbatch) WRITESTAGE();

        // indices for b + 2*stride (consumed by next iteration's GATHER)
        const int b2n = b + 2 * stride;
        if (b2n < nbatch) LOADIDX(b2n);
    }
#undef LOADIDX
#undef GATHER
#undef WRITESTAGE
#undef PSTEP
}

// ---------------------------------------------------------------------------
// Fallback (ws too small): direct per-edge MLP (round-1 kernel, known good).
// ---------------------------------------------------------------------------
extern "C" __global__ __launch_bounds__(256)
void edge_mlp_direct(const float* __restrict__ h_user,
                     const float* __restrict__ h_item,
                     const float* __restrict__ ef_orders,
                     const float* __restrict__ ef_rev,
                     const int* __restrict__ src_orders,
                     const int* __restrict__ dst_orders,
                     const int* __restrict__ src_rev,
                     const int* __restrict__ dst_rev,
                     const float* __restrict__ W1,
                     const float* __restrict__ b1,
                     const float* __restrict__ W2,
                     const float* __restrict__ b2,
                     const float* __restrict__ W3,
                     const float* __restrict__ b3,
                     float* __restrict__ out, int E)
{
    __shared__ unsigned short W1s[256][128];
    __shared__ float xbuf[4][256];
    __shared__ float h1s[4][128];
    const int tid = threadIdx.x;
    const int wave = tid >> 6, lane = tid & 63;
    const int f0 = 2 * lane;
    const int j2 = lane & 31;
    const int kb = (lane >> 5) * 64;

    for (int i = tid; i < 256 * 128; i += 256)
        W1s[i >> 7][i & 127] = f2bf(W1[i]);
    __syncthreads();

    float w1c0[16], w1c1[16];
    #pragma unroll
    for (int k = 0; k < 16; ++k) {
        w1c0[k] = W1[(256 + k) * 128 + f0];
        w1c1[k] = W1[(256 + k) * 128 + f0 + 1];
    }
    float w2r[64];
    #pragma unroll
    for (int kk = 0; kk < 64; ++kk)
        w2r[kk] = W2[(kb + kk) * 32 + j2];
    const float b10 = b1[f0], b11 = b1[f0 + 1];
    const float b2vv = b2[j2], w3vv = W3[j2], b3v = b3[0];

    const long twoE = 2L * E;
    for (long e = (long)blockIdx.x * 4 + wave; e < twoE; e += (long)gridDim.x * 4) {
        const bool rv = (e >= E);
        const int ee = (int)(rv ? e - E : e);
        const int s = (rv ? src_rev : src_orders)[ee];
        const int d = (rv ? dst_rev : dst_orders)[ee];
        const float* hs = rv ? h_item : h_user;
        const float* hd = rv ? h_user : h_item;
        const float* efp = rv ? ef_rev : ef_orders;

        xbuf[wave][lane]       = hs[(size_t)s * 128 + lane];
        xbuf[wave][64 + lane]  = hs[(size_t)s * 128 + 64 + lane];
        xbuf[wave][128 + lane] = hd[(size_t)d * 128 + lane];
        xbuf[wave][192 + lane] = hd[(size_t)d * 128 + 64 + lane];
        __builtin_amdgcn_wave_barrier();

        float p0 = b10, p1 = b11;
        #pragma unroll 8
        for (int k = 0; k < 256; ++k) {
            float xv = xbuf[wave][k];
            unsigned int w = *(const unsigned int*)&W1s[k][f0];
            p0 = fmaf(xv, bf2f_lo(w), p0);
            p1 = fmaf(xv, bf2f_hi(w), p1);
        }
        const float efv = efp[(size_t)ee * 16 + (lane & 15)];
        #pragma unroll
        for (int k = 0; k < 16; ++k) {
            float ek = __shfl(efv, k, 64);
            p0 = fmaf(ek, w1c0[k], p0);
            p1 = fmaf(ek, w1c1[k], p1);
        }
        p0 = fmaxf(p0, 0.0f);
        p1 = fmaxf(p1, 0.0f);

        *(float2*)&h1s[wave][f0] = make_float2(p0, p1);
        __builtin_amdgcn_wave_barrier();
        float acc = 0.0f;
        #pragma unroll
        for (int q = 0; q < 16; ++q) {
            float4 hv = *(const float4*)&h1s[wave][kb + q * 4];
            acc = fmaf(hv.x, w2r[4 * q + 0], acc);
            acc = fmaf(hv.y, w2r[4 * q + 1], acc);
            acc = fmaf(hv.z, w2r[4 * q + 2], acc);
            acc = fmaf(hv.w, w2r[4 * q + 3], acc);
        }
        __builtin_amdgcn_wave_barrier();
        acc += __shfl_xor(acc, 32, 64);
        float h2 = fmaxf(acc + b2vv, 0.0f);
        float v = h2 * w3vv;
        v += __shfl_xor(v, 16, 64);
        v += __shfl_xor(v, 8, 64);
        v += __shfl_xor(v, 4, 64);
        v += __shfl_xor(v, 2, 64);
        v += __shfl_xor(v, 1, 64);
        if (lane == 0)
            out[e] = 1.0f / (1.0f + __expf(-(v + b3v)));
    }
}

// ---------------------------------------------------------------------------
extern "C" void kernel_launch(void* const* d_in, const int* in_sizes, int n_in,
                              void* d_out, int out_size, void* d_ws, size_t ws_size,
                              hipStream_t stream)
{
    const float* h_user    = (const float*)d_in[0];
    const float* h_item    = (const float*)d_in[1];
    const float* ef_orders = (const float*)d_in[2];
    const float* ef_rev    = (const float*)d_in[3];
    const float* W1        = (const float*)d_in[4];
    const float* b1        = (const float*)d_in[5];
    const float* W2        = (const float*)d_in[6];
    const float* b2        = (const float*)d_in[7];
    const float* W3        = (const float*)d_in[8];
    const float* b3        = (const float*)d_in[9];
    const int* src_orders  = (const int*)d_in[10];
    const int* dst_orders  = (const int*)d_in[11];
    const int* src_rev     = (const int*)d_in[12];
    const int* dst_rev     = (const int*)d_in[13];

    const int n_user = in_sizes[0] / 128;
    const int n_item = in_sizes[1] / 128;
    const int E      = in_sizes[2] / 16;
    float* out = (float*)d_out;

    const size_t need = (size_t)(n_user + n_item) * 256;  // fp8: 1 B/elem
    if (ws_size >= need) {
        unsigned char* Yu = (unsigned char*)d_ws;
        unsigned char* Yi = Yu + (size_t)n_user * 256;
        precompute_mfma<<<2048, 256, 0, stream>>>(h_user, n_user, h_item, n_item, W1, Yu, Yi);
        edge_mfma<<<1024, 256, 0, stream>>>(Yu, Yi, ef_orders, ef_rev,
            src_orders, dst_orders, src_rev, dst_rev,
            W1, b1, W2, b2, W3, b3, out, E);
    } else {
        edge_mlp_direct<<<4096, 256, 0, stream>>>(h_user, h_item, ef_orders, ef_rev,
            src_orders, dst_orders, src_rev, dst_rev,
            W1, b1, W2, b2, W3, b3, out, E);
    }
}

// Round 8
// 125.314 us; speedup vs baseline: 1.7014x; 1.7014x over previous
//
#include <hip/hip_runtime.h>
#include <hip/hip_bf16.h>

typedef __attribute__((ext_vector_type(8))) short bfrag;   // 8 bf16 (A/B operand)
typedef __attribute__((ext_vector_type(4))) float facc;    // 4 f32  (C/D operand)
typedef __attribute__((ext_vector_type(2))) float f32x2;

static __device__ __forceinline__ float bf2f_lo(unsigned int u) {
    return __uint_as_float(u << 16);
}
static __device__ __forceinline__ float bf2f_hi(unsigned int u) {
    return __uint_as_float(u & 0xffff0000u);
}
static __device__ __forceinline__ unsigned short f2bf(float f) {
    __hip_bfloat16 b = __float2bfloat16(f);  // RNE
    return *reinterpret_cast<unsigned short*>(&b);
}

// ---------------------------------------------------------------------------
// Merged precompute: Y[row][0:128] = h@W1[0:128], Y[row][128:256] = h@W1[128:256]
// for BOTH node tables, output in OCP fp8-e4m3 (gather table 38 MB).
// MFMA 16x16x32 bf16; wave w owns cols [w*64, w*64+64); W1 frags in registers.
// D layout (verified): col = lane&15, row = (lane>>4)*4 + reg.
// ---------------------------------------------------------------------------
extern "C" __global__ __launch_bounds__(256)
void precompute_mfma(const float* __restrict__ hu, int nu,
                     const float* __restrict__ hi, int ni,
                     const float* __restrict__ W1,
                     unsigned char* __restrict__ Yu,
                     unsigned char* __restrict__ Yi)
{
    const int tid = threadIdx.x, wave = tid >> 6, lane = tid & 63;
    const int g = lane >> 4, e16 = lane & 15;
    const int c0 = wave * 64;

    bfrag bfr[4][4];
    #pragma unroll
    for (int nt = 0; nt < 4; ++nt) {
        const int j = c0 + nt * 16 + e16;
        #pragma unroll
        for (int kk = 0; kk < 4; ++kk) {
            bfrag v;
            #pragma unroll
            for (int i = 0; i < 8; ++i) {
                int k = kk * 32 + g * 8 + i;
                float w = (j < 128) ? W1[(size_t)k * 128 + j]
                                    : W1[(size_t)(128 + k) * 128 + (j - 128)];
                v[i] = (short)f2bf(w);
            }
            bfr[nt][kk] = v;
        }
    }

    const int tu = (nu + 15) >> 4, ti = (ni + 15) >> 4, tt = tu + ti;
    for (int tile = blockIdx.x; tile < tt; tile += gridDim.x) {
        const float* h; unsigned char* Y; int n, node0;
        if (tile < tu) { h = hu; Y = Yu; n = nu; node0 = tile * 16; }
        else           { h = hi; Y = Yi; n = ni; node0 = (tile - tu) * 16; }

        int arow = node0 + e16; if (arow >= n) arow = n - 1;
        facc acc[4] = {{0,0,0,0},{0,0,0,0},{0,0,0,0},{0,0,0,0}};
        #pragma unroll
        for (int kk = 0; kk < 4; ++kk) {
            const float* ap = h + (size_t)arow * 128 + kk * 32 + g * 8;
            float4 a0 = *(const float4*)ap;
            float4 a1v = *(const float4*)(ap + 4);
            bfrag af;
            af[0] = (short)f2bf(a0.x);  af[1] = (short)f2bf(a0.y);
            af[2] = (short)f2bf(a0.z);  af[3] = (short)f2bf(a0.w);
            af[4] = (short)f2bf(a1v.x); af[5] = (short)f2bf(a1v.y);
            af[6] = (short)f2bf(a1v.z); af[7] = (short)f2bf(a1v.w);
            #pragma unroll
            for (int nt = 0; nt < 4; ++nt)
                acc[nt] = __builtin_amdgcn_mfma_f32_16x16x32_bf16(af, bfr[nt][kk], acc[nt], 0, 0, 0);
        }
        #pragma unroll
        for (int nt = 0; nt < 4; ++nt) {
            unsigned int pk = __builtin_amdgcn_cvt_pk_fp8_f32(acc[nt][0], acc[nt][1], 0u, false);
            pk = __builtin_amdgcn_cvt_pk_fp8_f32(acc[nt][2], acc[nt][3], pk, true);
            #pragma unroll
            for (int r = 0; r < 4; ++r) {
                int row = node0 + g * 4 + r;
                if (row < n)
                    Y[(size_t)row * 256 + c0 + nt * 16 + e16] =
                        (unsigned char)(pk >> (8 * r));
            }
        }
    }
}

// ---------------------------------------------------------------------------
// Edge phase: 16 edges/wave/iter, edges-as-columns MFMA, software-pipelined.
// Round-8: request-count reduction via free k-slot permutation. Lane (g,e16)
// loads CONTIGUOUS 16B chunks (Y: [g*16,+16) and [64+g*16,+16); ef: one
// float4 at g*16) so each instruction coalesces to one 64B request per edge:
// Y 128->64 req/batch, ef 64->16. W2^T/W1c^T fragments and D1 reads use the
// matching permutation (k = (kk>>1)*64 + 16g + (kk&1)*8 + i; ef feature 4g+i
// in slot (g,i<4), bias at (g0,i4)) — dot products are permutation-invariant.
// Structure/order identical to round 6 (known-good 162 us baseline).
// ---------------------------------------------------------------------------
extern "C" __global__ __launch_bounds__(256, 3)
void edge_mfma(const unsigned char* __restrict__ Yu,
               const unsigned char* __restrict__ Yi,
               const float* __restrict__ ef_orders,
               const float* __restrict__ ef_rev,
               const int* __restrict__ src_orders,
               const int* __restrict__ dst_orders,
               const int* __restrict__ src_rev,
               const int* __restrict__ dst_rev,
               const float* __restrict__ W1,
               const float* __restrict__ b1,
               const float* __restrict__ W2,
               const float* __restrict__ b2,
               const float* __restrict__ W3,
               const float* __restrict__ b3,
               float* __restrict__ out, int E)
{
    __shared__ __align__(16) unsigned short d1_lds[4][16][128];  // 16 KB
    const int tid = threadIdx.x, wave = tid >> 6, lane = tid & 63;
    const int g = lane >> 4, e16 = lane & 15;
    unsigned short (*my_lds)[128] = d1_lds[wave];
    const int swzb = (e16 & 7) << 3;   // bf16-unit XOR, 16B granule

    // A frags for ef GEMM, spread mapping: k-slot (g, i<4) <-> ef[4g+i];
    // slot (g==0, i==4) carries b1 (B supplies 1.0 there); all else zero.
    bfrag a1[8];
    #pragma unroll
    for (int t = 0; t < 8; ++t) {
        bfrag v;
        #pragma unroll
        for (int i = 0; i < 8; ++i) {
            unsigned short s16 = 0;
            if (i < 4)                s16 = f2bf(W1[(size_t)(256 + 4 * g + i) * 128 + t * 16 + e16]);
            else if (i == 4 && g == 0) s16 = f2bf(b1[t * 16 + e16]);
            v[i] = (short)s16;
        }
        a1[t] = v;
    }
    // W2^T A-frags with the gather permutation:
    // slot (kk,g,i) <-> k = (kk>>1)*64 + 16g + (kk&1)*8 + i
    bfrag w2t[2][4];
    #pragma unroll
    for (int nt = 0; nt < 2; ++nt)
        #pragma unroll
        for (int kk = 0; kk < 4; ++kk) {
            bfrag v;
            #pragma unroll
            for (int i = 0; i < 8; ++i) {
                int k = (kk >> 1) * 64 + 16 * g + (kk & 1) * 8 + i;
                v[i] = (short)f2bf(W2[(size_t)k * 32 + nt * 16 + e16]);
            }
            w2t[nt][kk] = v;
        }
    float b2v[2][4], w3v[2][4];
    #pragma unroll
    for (int nt = 0; nt < 2; ++nt)
        #pragma unroll
        for (int r = 0; r < 4; ++r) {
            b2v[nt][r] = b2[nt * 16 + g * 4 + r];
            w3v[nt][r] = W3[nt * 16 + g * 4 + r];
        }
    const float b3s = b3[0];

    const long twoE = 2L * E;
    const int nbatch = (int)((twoE + 15) >> 4);
    const int stride = gridDim.x * 4;
    int b = blockIdx.x * 4 + wave;

    // pipeline state — all named scalars/vectors (register-resident)
    int s_pf = 0, d_pf = 0;
    uint4 ysA, ysB, ydA, ydB;
    float4 efq = make_float4(0, 0, 0, 0);

#define LOADIDX(BB) do {                                                      \
        long el_ = ((long)(BB) << 4) + e16;                                   \
        if (el_ >= twoE) el_ = twoE - 1;                                      \
        const bool rv_ = el_ >= E;                                            \
        const int ee_ = (int)(rv_ ? el_ - E : el_);                           \
        s_pf = (rv_ ? src_rev : src_orders)[ee_];                             \
        d_pf = (rv_ ? dst_rev : dst_orders)[ee_];                             \
    } while (0)

#define GATHER(BB) do {                                                       \
        long el_ = ((long)(BB) << 4) + e16;                                   \
        if (el_ >= twoE) el_ = twoE - 1;                                      \
        const bool rv_ = el_ >= E;                                            \
        const int ee_ = (int)(rv_ ? el_ - E : el_);                           \
        const unsigned char* ps_ = (rv_ ? Yi : Yu) + (size_t)s_pf * 256 + g * 16; \
        const unsigned char* pd_ = (rv_ ? Yu : Yi) + (size_t)d_pf * 256 + 128 + g * 16; \
        ysA = *(const uint4*)(ps_);       ysB = *(const uint4*)(ps_ + 64);    \
        ydA = *(const uint4*)(pd_);       ydB = *(const uint4*)(pd_ + 64);    \
        efq = *(const float4*)((rv_ ? ef_rev : ef_orders) + (size_t)ee_ * 16 + g * 4); \
    } while (0)

#define PSTEP(KK, YSL, YSH, YDL, YDH) do {                                    \
        const int dlo_ = (((KK) >> 1) * 64 + 16 * g + ((KK) & 1) * 8) ^ swzb; \
        uint4 wv = *(const uint4*)&my_lds[e16][dlo_];                         \
        f32x2 s01 = __builtin_amdgcn_cvt_pk_f32_fp8(YSL, false);              \
        f32x2 s23 = __builtin_amdgcn_cvt_pk_f32_fp8(YSL, true);               \
        f32x2 s45 = __builtin_amdgcn_cvt_pk_f32_fp8(YSH, false);              \
        f32x2 s67 = __builtin_amdgcn_cvt_pk_f32_fp8(YSH, true);               \
        f32x2 d01 = __builtin_amdgcn_cvt_pk_f32_fp8(YDL, false);              \
        f32x2 d23 = __builtin_amdgcn_cvt_pk_f32_fp8(YDL, true);               \
        f32x2 d45 = __builtin_amdgcn_cvt_pk_f32_fp8(YDH, false);              \
        f32x2 d67 = __builtin_amdgcn_cvt_pk_f32_fp8(YDH, true);               \
        float p0 = s01[0] + d01[0] + bf2f_lo(wv.x);                           \
        float p1 = s01[1] + d01[1] + bf2f_hi(wv.x);                           \
        float p2 = s23[0] + d23[0] + bf2f_lo(wv.y);                           \
        float p3 = s23[1] + d23[1] + bf2f_hi(wv.y);                           \
        float p4 = s45[0] + d45[0] + bf2f_lo(wv.z);                           \
        float p5 = s45[1] + d45[1] + bf2f_hi(wv.z);                           \
        float p6 = s67[0] + d67[0] + bf2f_lo(wv.w);                           \
        float p7 = s67[1] + d67[1] + bf2f_hi(wv.w);                           \
        bfrag pa;                                                             \
        pa[0] = (short)f2bf(fmaxf(p0, 0.f)); pa[1] = (short)f2bf(fmaxf(p1, 0.f)); \
        pa[2] = (short)f2bf(fmaxf(p2, 0.f)); pa[3] = (short)f2bf(fmaxf(p3, 0.f)); \
        pa[4] = (short)f2bf(fmaxf(p4, 0.f)); pa[5] = (short)f2bf(fmaxf(p5, 0.f)); \
        pa[6] = (short)f2bf(fmaxf(p6, 0.f)); pa[7] = (short)f2bf(fmaxf(p7, 0.f)); \
        acc2a = __builtin_amdgcn_mfma_f32_16x16x32_bf16(w2t[0][KK], pa, acc2a, 0, 0, 0); \
        acc2b = __builtin_amdgcn_mfma_f32_16x16x32_bf16(w2t[1][KK], pa, acc2b, 0, 0, 0); \
    } while (0)

    if (b < nbatch) {
        LOADIDX(b);
        GATHER(b);
        if (b + stride < nbatch) LOADIDX(b + stride);
    }

    for (; b < nbatch; b += stride) {
        // B frag from prefetched ef: slots i<4 = ef[4g+i]; (g0,i4) = 1.0
        bfrag eb;
        #pragma unroll
        for (int i = 0; i < 8; ++i) eb[i] = 0;
        eb[0] = (short)f2bf(efq.x); eb[1] = (short)f2bf(efq.y);
        eb[2] = (short)f2bf(efq.z); eb[3] = (short)f2bf(efq.w);
        if (g == 0) eb[4] = (short)0x3F80;  // bf16 1.0 -> adds b1[n]

        // D1 = W1c^T @ ef^T + b1 -> bf16 LDS transpose (swizzled)
        #pragma unroll
        for (int t = 0; t < 8; ++t) {
            facc zero = {0, 0, 0, 0};
            facc d1 = __builtin_amdgcn_mfma_f32_16x16x32_bf16(a1[t], eb, zero, 0, 0, 0);
            ushort4 u;
            u.x = f2bf(d1[0]); u.y = f2bf(d1[1]); u.z = f2bf(d1[2]); u.w = f2bf(d1[3]);
            *(ushort4*)&my_lds[e16][(t * 16 + g * 4) ^ swzb] = u;
        }

        // P build + second GEMM (consumes prefetched ys/yd registers)
        facc acc2a = {0, 0, 0, 0}, acc2b = {0, 0, 0, 0};
        PSTEP(0, ysA.x, ysA.y, ydA.x, ydA.y);
        PSTEP(1, ysA.z, ysA.w, ydA.z, ydA.w);
        PSTEP(2, ysB.x, ysB.y, ydB.x, ydB.y);
        PSTEP(3, ysB.z, ysB.w, ydB.z, ydB.w);

        // issue next batch's gathers now that ys/yd are consumed;
        // latency hides under tail + next iter's D1 phase + wave TLP
        const int bn = b + stride;
        if (bn < nbatch) GATHER(bn);

        // tail: relu(h2+b2) . W3, reduce over g-groups, sigmoid, store
        float h3 = 0.f;
        #pragma unroll
        for (int r = 0; r < 4; ++r) {
            float h2 = fmaxf(acc2a[r] + b2v[0][r], 0.f);
            h3 = fmaf(h2, w3v[0][r], h3);
        }
        #pragma unroll
        for (int r = 0; r < 4; ++r) {
            float h2 = fmaxf(acc2b[r] + b2v[1][r], 0.f);
            h3 = fmaf(h2, w3v[1][r], h3);
        }
        h3 += __shfl_xor(h3, 16, 64);
        h3 += __shfl_xor(h3, 32, 64);
        const long el = ((long)b << 4) + lane;
        if (lane < 16 && el < twoE)
            out[el] = 1.f / (1.f + __expf(-(h3 + b3s)));

        // indices for b + 2*stride (consumed by next iteration's GATHER)
        const int b2n = b + 2 * stride;
        if (b2n < nbatch) LOADIDX(b2n);
    }
#undef LOADIDX
#undef GATHER
#undef PSTEP
}

// ---------------------------------------------------------------------------
// Fallback (ws too small): direct per-edge MLP (round-1 kernel, known good).
// ---------------------------------------------------------------------------
extern "C" __global__ __launch_bounds__(256)
void edge_mlp_direct(const float* __restrict__ h_user,
                     const float* __restrict__ h_item,
                     const float* __restrict__ ef_orders,
                     const float* __restrict__ ef_rev,
                     const int* __restrict__ src_orders,
                     const int* __restrict__ dst_orders,
                     const int* __restrict__ src_rev,
                     const int* __restrict__ dst_rev,
                     const float* __restrict__ W1,
                     const float* __restrict__ b1,
                     const float* __restrict__ W2,
                     const float* __restrict__ b2,
                     const float* __restrict__ W3,
                     const float* __restrict__ b3,
                     float* __restrict__ out, int E)
{
    __shared__ unsigned short W1s[256][128];
    __shared__ float xbuf[4][256];
    __shared__ float h1s[4][128];
    const int tid = threadIdx.x;
    const int wave = tid >> 6, lane = tid & 63;
    const int f0 = 2 * lane;
    const int j2 = lane & 31;
    const int kb = (lane >> 5) * 64;

    for (int i = tid; i < 256 * 128; i += 256)
        W1s[i >> 7][i & 127] = f2bf(W1[i]);
    __syncthreads();

    float w1c0[16], w1c1[16];
    #pragma unroll
    for (int k = 0; k < 16; ++k) {
        w1c0[k] = W1[(256 + k) * 128 + f0];
        w1c1[k] = W1[(256 + k) * 128 + f0 + 1];
    }
    float w2r[64];
    #pragma unroll
    for (int kk = 0; kk < 64; ++kk)
        w2r[kk] = W2[(kb + kk) * 32 + j2];
    const float b10 = b1[f0], b11 = b1[f0 + 1];
    const float b2vv = b2[j2], w3vv = W3[j2], b3v = b3[0];

    const long twoE = 2L * E;
    for (long e = (long)blockIdx.x * 4 + wave; e < twoE; e += (long)gridDim.x * 4) {
        const bool rv = (e >= E);
        const int ee = (int)(rv ? e - E : e);
        const int s = (rv ? src_rev : src_orders)[ee];
        const int d = (rv ? dst_rev : dst_orders)[ee];
        const float* hs = rv ? h_item : h_user;
        const float* hd = rv ? h_user : h_item;
        const float* efp = rv ? ef_rev : ef_orders;

        xbuf[wave][lane]       = hs[(size_t)s * 128 + lane];
        xbuf[wave][64 + lane]  = hs[(size_t)s * 128 + 64 + lane];
        xbuf[wave][128 + lane] = hd[(size_t)d * 128 + lane];
        xbuf[wave][192 + lane] = hd[(size_t)d * 128 + 64 + lane];
        __builtin_amdgcn_wave_barrier();

        float p0 = b10, p1 = b11;
        #pragma unroll 8
        for (int k = 0; k < 256; ++k) {
            float xv = xbuf[wave][k];
            unsigned int w = *(const unsigned int*)&W1s[k][f0];
            p0 = fmaf(xv, bf2f_lo(w), p0);
            p1 = fmaf(xv, bf2f_hi(w), p1);
        }
        const float efv = efp[(size_t)ee * 16 + (lane & 15)];
        #pragma unroll
        for (int k = 0; k < 16; ++k) {
            float ek = __shfl(efv, k, 64);
            p0 = fmaf(ek, w1c0[k], p0);
            p1 = fmaf(ek, w1c1[k], p1);
        }
        p0 = fmaxf(p0, 0.0f);
        p1 = fmaxf(p1, 0.0f);

        *(float2*)&h1s[wave][f0] = make_float2(p0, p1);
        __builtin_amdgcn_wave_barrier();
        float acc = 0.0f;
        #pragma unroll
        for (int q = 0; q < 16; ++q) {
            float4 hv = *(const float4*)&h1s[wave][kb + q * 4];
            acc = fmaf(hv.x, w2r[4 * q + 0], acc);
            acc = fmaf(hv.y, w2r[4 * q + 1], acc);
            acc = fmaf(hv.z, w2r[4 * q + 2], acc);
            acc = fmaf(hv.w, w2r[4 * q + 3], acc);
        }
        __builtin_amdgcn_wave_barrier();
        acc += __shfl_xor(acc, 32, 64);
        float h2 = fmaxf(acc + b2vv, 0.0f);
        float v = h2 * w3vv;
        v += __shfl_xor(v, 16, 64);
        v += __shfl_xor(v, 8, 64);
        v += __shfl_xor(v, 4, 64);
        v += __shfl_xor(v, 2, 64);
        v += __shfl_xor(v, 1, 64);
        if (lane == 0)
            out[e] = 1.0f / (1.0f + __expf(-(v + b3v)));
    }
}

// ---------------------------------------------------------------------------
extern "C" void kernel_launch(void* const* d_in, const int* in_sizes, int n_in,
                              void* d_out, int out_size, void* d_ws, size_t ws_size,
                              hipStream_t stream)
{
    const float* h_user    = (const float*)d_in[0];
    const float* h_item    = (const float*)d_in[1];
    const float* ef_orders = (const float*)d_in[2];
    const float* ef_rev    = (const float*)d_in[3];
    const float* W1        = (const float*)d_in[4];
    const float* b1        = (const float*)d_in[5];
    const float* W2        = (const float*)d_in[6];
    const float* b2        = (const float*)d_in[7];
    const float* W3        = (const float*)d_in[8];
    const float* b3        = (const float*)d_in[9];
    const int* src_orders  = (const int*)d_in[10];
    const int* dst_orders  = (const int*)d_in[11];
    const int* src_rev     = (const int*)d_in[12];
    const int* dst_rev     = (const int*)d_in[13];

    const int n_user = in_sizes[0] / 128;
    const int n_item = in_sizes[1] / 128;
    const int E      = in_sizes[2] / 16;
    float* out = (float*)d_out;

    const size_t need = (size_t)(n_user + n_item) * 256;  // fp8: 1 B/elem
    if (ws_size >= need) {
        unsigned char* Yu = (unsigned char*)d_ws;
        unsigned char* Yi = Yu + (size_t)n_user * 256;
        precompute_mfma<<<2048, 256, 0, stream>>>(h_user, n_user, h_item, n_item, W1, Yu, Yi);
        edge_mfma<<<1024, 256, 0, stream>>>(Yu, Yi, ef_orders, ef_rev,
            src_orders, dst_orders, src_rev, dst_rev,
            W1, b1, W2, b2, W3, b3, out, E);
    } else {
        edge_mlp_direct<<<4096, 256, 0, stream>>>(h_user, h_item, ef_orders, ef_rev,
            src_orders, dst_orders, src_rev, dst_rev,
            W1, b1, W2, b2, W3, b3, out, E);
    }
}

// Round 9
// 112.945 us; speedup vs baseline: 1.8877x; 1.1095x over previous
//
#include <hip/hip_runtime.h>
#include <hip/hip_bf16.h>

typedef __attribute__((ext_vector_type(8))) short bfrag;   // 8 bf16 (A/B operand)
typedef __attribute__((ext_vector_type(4))) float facc;    // 4 f32  (C/D operand)
typedef __attribute__((ext_vector_type(2))) float f32x2;

static __device__ __forceinline__ float bf2f_lo(unsigned int u) {
    return __uint_as_float(u << 16);
}
static __device__ __forceinline__ float bf2f_hi(unsigned int u) {
    return __uint_as_float(u & 0xffff0000u);
}
static __device__ __forceinline__ unsigned short f2bf(float f) {
    __hip_bfloat16 b = __float2bfloat16(f);  // RNE
    return *reinterpret_cast<unsigned short*>(&b);
}

// ---------------------------------------------------------------------------
// Precompute (round-9 rework): Y[row][0:256] = h[row] @ [W1a | W1b], fp8-e4m3.
//  - block stages one 16-row h tile in padded LDS (f32 [16][132], pad kills
//    the stride-512 bank collision; reads/writes verified bank-balanced),
//    loaded ONCE per block with fully-coalesced 512B-per-row float4 loads
//    (was: each of 4 waves redundantly re-loading the tile, 4x L3 traffic)
//  - MFMA operands swapped vs rounds 2-8: A = W1 fragments (loop-invariant
//    registers), B = h from LDS. D then lands col=node(e16), row=j-quad ->
//    each lane packs 4 consecutive Y columns of ONE row into a single u32
//    store (was 16 scattered byte-stores per tile)
//  - double-buffered LDS; next tile's global loads issue before this tile's
//    compute, vmcnt lands at the post-barrier LDS write
// ---------------------------------------------------------------------------
extern "C" __global__ __launch_bounds__(256)
void precompute_mfma(const float* __restrict__ hu, int nu,
                     const float* __restrict__ hi, int ni,
                     const float* __restrict__ W1,
                     unsigned char* __restrict__ Yu,
                     unsigned char* __restrict__ Yi)
{
    __shared__ __align__(16) float hstage[2][16][132];
    const int tid = threadIdx.x, wave = tid >> 6, lane = tid & 63;
    const int g = lane >> 4, e16 = lane & 15;
    const int c0 = wave * 64;

    // A-frags: W1 columns j = c0 + nt*16 + e16, k-slot = kk*32 + g*8 + i.
    // (lane&15 indexes the M dimension of A = the j tile; same init as the
    //  old B-frag — operand roles swap, lane layout is identical.)
    bfrag aw1[4][4];
    #pragma unroll
    for (int nt = 0; nt < 4; ++nt) {
        const int j = c0 + nt * 16 + e16;
        #pragma unroll
        for (int kk = 0; kk < 4; ++kk) {
            bfrag v;
            #pragma unroll
            for (int i = 0; i < 8; ++i) {
                int k = kk * 32 + g * 8 + i;
                float w = (j < 128) ? W1[(size_t)k * 128 + j]
                                    : W1[(size_t)(128 + k) * 128 + (j - 128)];
                v[i] = (short)f2bf(w);
            }
            aw1[nt][kk] = v;
        }
    }

    // staging geometry: thread t, chunk q in {0,1}: row = q*8 + (t>>5),
    // col-dword = (t&31)*4  -> per instr: 2 rows x 512B fully coalesced.
    const int srow = tid >> 5;          // 0..7
    const int scol = (tid & 31) * 4;    // 0..124

    const int tu = (nu + 15) >> 4, ti = (ni + 15) >> 4, tt = tu + ti;
    const int stride = gridDim.x;
    int tile = blockIdx.x;

    const float* hs_c = hu; unsigned char* Y_c = Yu; int n_c = nu, node0_c = 0;
    const float* hs_n; unsigned char* Y_n; int n_n, node0_n;
    float4 sA, sB;

#define SETSRC(T, HS, YP, NN, N0) do {                                        \
        if ((T) < tu) { HS = hu; YP = Yu; NN = nu; N0 = (T) * 16; }           \
        else          { HS = hi; YP = Yi; NN = ni; N0 = ((T) - tu) * 16; }    \
    } while (0)

#define LOADTILE(HS, NN, N0) do {                                             \
        int rA_ = (N0) + srow;     if (rA_ >= (NN)) rA_ = (NN) - 1;           \
        int rB_ = (N0) + 8 + srow; if (rB_ >= (NN)) rB_ = (NN) - 1;           \
        sA = *(const float4*)((HS) + (size_t)rA_ * 128 + scol);               \
        sB = *(const float4*)((HS) + (size_t)rB_ * 128 + scol);               \
    } while (0)

#define STAGE(BUF) do {                                                       \
        *(float4*)&hstage[BUF][srow][scol]     = sA;                          \
        *(float4*)&hstage[BUF][8 + srow][scol] = sB;                          \
    } while (0)

    if (tile < tt) {
        SETSRC(tile, hs_c, Y_c, n_c, node0_c);
        LOADTILE(hs_c, n_c, node0_c);
        STAGE(0);
    }
    __syncthreads();
    int buf = 0;

    for (; tile < tt; tile += stride) {
        const int tn = tile + stride;
        if (tn < tt) {
            SETSRC(tn, hs_n, Y_n, n_n, node0_n);
            LOADTILE(hs_n, n_n, node0_n);   // in flight across compute
        }

        // compute: B-frags from LDS (2x ds_read_b128 per kk), 16 MFMA
        facc acc[4] = {{0,0,0,0},{0,0,0,0},{0,0,0,0},{0,0,0,0}};
        #pragma unroll
        for (int kk = 0; kk < 4; ++kk) {
            const float4 b0 = *(const float4*)&hstage[buf][e16][kk * 32 + g * 8];
            const float4 b1 = *(const float4*)&hstage[buf][e16][kk * 32 + g * 8 + 4];
            bfrag bf;
            bf[0] = (short)f2bf(b0.x); bf[1] = (short)f2bf(b0.y);
            bf[2] = (short)f2bf(b0.z); bf[3] = (short)f2bf(b0.w);
            bf[4] = (short)f2bf(b1.x); bf[5] = (short)f2bf(b1.y);
            bf[6] = (short)f2bf(b1.z); bf[7] = (short)f2bf(b1.w);
            #pragma unroll
            for (int nt = 0; nt < 4; ++nt)
                acc[nt] = __builtin_amdgcn_mfma_f32_16x16x32_bf16(aw1[nt][kk], bf, acc[nt], 0, 0, 0);
        }

        // store: lane packs Y[node][j..j+3] (j = c0+nt*16+g*4) into one u32
        const int node = node0_c + e16;
        if (node < n_c) {
            #pragma unroll
            for (int nt = 0; nt < 4; ++nt) {
                unsigned int pk = __builtin_amdgcn_cvt_pk_fp8_f32(acc[nt][0], acc[nt][1], 0u, false);
                pk = __builtin_amdgcn_cvt_pk_fp8_f32(acc[nt][2], acc[nt][3], pk, true);
                *(unsigned int*)&Y_c[(size_t)node * 256 + c0 + nt * 16 + g * 4] = pk;
            }
        }

        if (tn < tt) {
            __syncthreads();            // all waves done reading both buffers
            STAGE(buf ^ 1);             // vmcnt wait on sA/sB lands here
            __syncthreads();
            hs_c = hs_n; Y_c = Y_n; n_c = n_n; node0_c = node0_n;
        }
        buf ^= 1;
    }
#undef SETSRC
#undef LOADTILE
#undef STAGE
}

// ---------------------------------------------------------------------------
// Edge phase (unchanged from round 8, the 82-req/batch winner): 16 edges/wave,
// edges-as-columns MFMA, contiguous 16B per-lane chunks coalescing to one 64B
// request per edge via the free k-slot permutation; fp8 Y; software-pipelined.
// ---------------------------------------------------------------------------
extern "C" __global__ __launch_bounds__(256, 3)
void edge_mfma(const unsigned char* __restrict__ Yu,
               const unsigned char* __restrict__ Yi,
               const float* __restrict__ ef_orders,
               const float* __restrict__ ef_rev,
               const int* __restrict__ src_orders,
               const int* __restrict__ dst_orders,
               const int* __restrict__ src_rev,
               const int* __restrict__ dst_rev,
               const float* __restrict__ W1,
               const float* __restrict__ b1,
               const float* __restrict__ W2,
               const float* __restrict__ b2,
               const float* __restrict__ W3,
               const float* __restrict__ b3,
               float* __restrict__ out, int E)
{
    __shared__ __align__(16) unsigned short d1_lds[4][16][128];  // 16 KB
    const int tid = threadIdx.x, wave = tid >> 6, lane = tid & 63;
    const int g = lane >> 4, e16 = lane & 15;
    unsigned short (*my_lds)[128] = d1_lds[wave];
    const int swzb = (e16 & 7) << 3;   // bf16-unit XOR, 16B granule

    // A frags for ef GEMM, spread mapping: k-slot (g, i<4) <-> ef[4g+i];
    // slot (g==0, i==4) carries b1 (B supplies 1.0 there); all else zero.
    bfrag a1[8];
    #pragma unroll
    for (int t = 0; t < 8; ++t) {
        bfrag v;
        #pragma unroll
        for (int i = 0; i < 8; ++i) {
            unsigned short s16 = 0;
            if (i < 4)                s16 = f2bf(W1[(size_t)(256 + 4 * g + i) * 128 + t * 16 + e16]);
            else if (i == 4 && g == 0) s16 = f2bf(b1[t * 16 + e16]);
            v[i] = (short)s16;
        }
        a1[t] = v;
    }
    // W2^T A-frags with the gather permutation:
    // slot (kk,g,i) <-> k = (kk>>1)*64 + 16g + (kk&1)*8 + i
    bfrag w2t[2][4];
    #pragma unroll
    for (int nt = 0; nt < 2; ++nt)
        #pragma unroll
        for (int kk = 0; kk < 4; ++kk) {
            bfrag v;
            #pragma unroll
            for (int i = 0; i < 8; ++i) {
                int k = (kk >> 1) * 64 + 16 * g + (kk & 1) * 8 + i;
                v[i] = (short)f2bf(W2[(size_t)k * 32 + nt * 16 + e16]);
            }
            w2t[nt][kk] = v;
        }
    float b2v[2][4], w3v[2][4];
    #pragma unroll
    for (int nt = 0; nt < 2; ++nt)
        #pragma unroll
        for (int r = 0; r < 4; ++r) {
            b2v[nt][r] = b2[nt * 16 + g * 4 + r];
            w3v[nt][r] = W3[nt * 16 + g * 4 + r];
        }
    const float b3s = b3[0];

    const long twoE = 2L * E;
    const int nbatch = (int)((twoE + 15) >> 4);
    const int stride = gridDim.x * 4;
    int b = blockIdx.x * 4 + wave;

    // pipeline state — all named scalars/vectors (register-resident)
    int s_pf = 0, d_pf = 0;
    uint4 ysA, ysB, ydA, ydB;
    float4 efq = make_float4(0, 0, 0, 0);

#define LOADIDX(BB) do {                                                      \
        long el_ = ((long)(BB) << 4) + e16;                                   \
        if (el_ >= twoE) el_ = twoE - 1;                                      \
        const bool rv_ = el_ >= E;                                            \
        const int ee_ = (int)(rv_ ? el_ - E : el_);                           \
        s_pf = (rv_ ? src_rev : src_orders)[ee_];                             \
        d_pf = (rv_ ? dst_rev : dst_orders)[ee_];                             \
    } while (0)

#define GATHER(BB) do {                                                       \
        long el_ = ((long)(BB) << 4) + e16;                                   \
        if (el_ >= twoE) el_ = twoE - 1;                                      \
        const bool rv_ = el_ >= E;                                            \
        const int ee_ = (int)(rv_ ? el_ - E : el_);                           \
        const unsigned char* ps_ = (rv_ ? Yi : Yu) + (size_t)s_pf * 256 + g * 16; \
        const unsigned char* pd_ = (rv_ ? Yu : Yi) + (size_t)d_pf * 256 + 128 + g * 16; \
        ysA = *(const uint4*)(ps_);       ysB = *(const uint4*)(ps_ + 64);    \
        ydA = *(const uint4*)(pd_);       ydB = *(const uint4*)(pd_ + 64);    \
        efq = *(const float4*)((rv_ ? ef_rev : ef_orders) + (size_t)ee_ * 16 + g * 4); \
    } while (0)

#define PSTEP(KK, YSL, YSH, YDL, YDH) do {                                    \
        const int dlo_ = (((KK) >> 1) * 64 + 16 * g + ((KK) & 1) * 8) ^ swzb; \
        uint4 wv = *(const uint4*)&my_lds[e16][dlo_];                         \
        f32x2 s01 = __builtin_amdgcn_cvt_pk_f32_fp8(YSL, false);              \
        f32x2 s23 = __builtin_amdgcn_cvt_pk_f32_fp8(YSL, true);               \
        f32x2 s45 = __builtin_amdgcn_cvt_pk_f32_fp8(YSH, false);              \
        f32x2 s67 = __builtin_amdgcn_cvt_pk_f32_fp8(YSH, true);               \
        f32x2 d01 = __builtin_amdgcn_cvt_pk_f32_fp8(YDL, false);              \
        f32x2 d23 = __builtin_amdgcn_cvt_pk_f32_fp8(YDL, true);               \
        f32x2 d45 = __builtin_amdgcn_cvt_pk_f32_fp8(YDH, false);              \
        f32x2 d67 = __builtin_amdgcn_cvt_pk_f32_fp8(YDH, true);               \
        float p0 = s01[0] + d01[0] + bf2f_lo(wv.x);                           \
        float p1 = s01[1] + d01[1] + bf2f_hi(wv.x);                           \
        float p2 = s23[0] + d23[0] + bf2f_lo(wv.y);                           \
        float p3 = s23[1] + d23[1] + bf2f_hi(wv.y);                           \
        float p4 = s45[0] + d45[0] + bf2f_lo(wv.z);                           \
        float p5 = s45[1] + d45[1] + bf2f_hi(wv.z);                           \
        float p6 = s67[0] + d67[0] + bf2f_lo(wv.w);                           \
        float p7 = s67[1] + d67[1] + bf2f_hi(wv.w);                           \
        bfrag pa;                                                             \
        pa[0] = (short)f2bf(fmaxf(p0, 0.f)); pa[1] = (short)f2bf(fmaxf(p1, 0.f)); \
        pa[2] = (short)f2bf(fmaxf(p2, 0.f)); pa[3] = (short)f2bf(fmaxf(p3, 0.f)); \
        pa[4] = (short)f2bf(fmaxf(p4, 0.f)); pa[5] = (short)f2bf(fmaxf(p5, 0.f)); \
        pa[6] = (short)f2bf(fmaxf(p6, 0.f)); pa[7] = (short)f2bf(fmaxf(p7, 0.f)); \
        acc2a = __builtin_amdgcn_mfma_f32_16x16x32_bf16(w2t[0][KK], pa, acc2a, 0, 0, 0); \
        acc2b = __builtin_amdgcn_mfma_f32_16x16x32_bf16(w2t[1][KK], pa, acc2b, 0, 0, 0); \
    } while (0)

    if (b < nbatch) {
        LOADIDX(b);
        GATHER(b);
        if (b + stride < nbatch) LOADIDX(b + stride);
    }

    for (; b < nbatch; b += stride) {
        // B frag from prefetched ef: slots i<4 = ef[4g+i]; (g0,i4) = 1.0
        bfrag eb;
        #pragma unroll
        for (int i = 0; i < 8; ++i) eb[i] = 0;
        eb[0] = (short)f2bf(efq.x); eb[1] = (short)f2bf(efq.y);
        eb[2] = (short)f2bf(efq.z); eb[3] = (short)f2bf(efq.w);
        if (g == 0) eb[4] = (short)0x3F80;  // bf16 1.0 -> adds b1[n]

        // D1 = W1c^T @ ef^T + b1 -> bf16 LDS transpose (swizzled)
        #pragma unroll
        for (int t = 0; t < 8; ++t) {
            facc zero = {0, 0, 0, 0};
            facc d1 = __builtin_amdgcn_mfma_f32_16x16x32_bf16(a1[t], eb, zero, 0, 0, 0);
            ushort4 u;
            u.x = f2bf(d1[0]); u.y = f2bf(d1[1]); u.z = f2bf(d1[2]); u.w = f2bf(d1[3]);
            *(ushort4*)&my_lds[e16][(t * 16 + g * 4) ^ swzb] = u;
        }

        // P build + second GEMM (consumes prefetched ys/yd registers)
        facc acc2a = {0, 0, 0, 0}, acc2b = {0, 0, 0, 0};
        PSTEP(0, ysA.x, ysA.y, ydA.x, ydA.y);
        PSTEP(1, ysA.z, ysA.w, ydA.z, ydA.w);
        PSTEP(2, ysB.x, ysB.y, ydB.x, ydB.y);
        PSTEP(3, ysB.z, ysB.w, ydB.z, ydB.w);

        // issue next batch's gathers now that ys/yd are consumed;
        // latency hides under tail + next iter's D1 phase + wave TLP
        const int bn = b + stride;
        if (bn < nbatch) GATHER(bn);

        // tail: relu(h2+b2) . W3, reduce over g-groups, sigmoid, store
        float h3 = 0.f;
        #pragma unroll
        for (int r = 0; r < 4; ++r) {
            float h2 = fmaxf(acc2a[r] + b2v[0][r], 0.f);
            h3 = fmaf(h2, w3v[0][r], h3);
        }
        #pragma unroll
        for (int r = 0; r < 4; ++r) {
            float h2 = fmaxf(acc2b[r] + b2v[1][r], 0.f);
            h3 = fmaf(h2, w3v[1][r], h3);
        }
        h3 += __shfl_xor(h3, 16, 64);
        h3 += __shfl_xor(h3, 32, 64);
        const long el = ((long)b << 4) + lane;
        if (lane < 16 && el < twoE)
            out[el] = 1.f / (1.f + __expf(-(h3 + b3s)));

        // indices for b + 2*stride (consumed by next iteration's GATHER)
        const int b2n = b + 2 * stride;
        if (b2n < nbatch) LOADIDX(b2n);
    }
#undef LOADIDX
#undef GATHER
#undef PSTEP
}

// ---------------------------------------------------------------------------
// Fallback (ws too small): direct per-edge MLP (round-1 kernel, known good).
// ---------------------------------------------------------------------------
extern "C" __global__ __launch_bounds__(256)
void edge_mlp_direct(const float* __restrict__ h_user,
                     const float* __restrict__ h_item,
                     const float* __restrict__ ef_orders,
                     const float* __restrict__ ef_rev,
                     const int* __restrict__ src_orders,
                     const int* __restrict__ dst_orders,
                     const int* __restrict__ src_rev,
                     const int* __restrict__ dst_rev,
                     const float* __restrict__ W1,
                     const float* __restrict__ b1,
                     const float* __restrict__ W2,
                     const float* __restrict__ b2,
                     const float* __restrict__ W3,
                     const float* __restrict__ b3,
                     float* __restrict__ out, int E)
{
    __shared__ unsigned short W1s[256][128];
    __shared__ float xbuf[4][256];
    __shared__ float h1s[4][128];
    const int tid = threadIdx.x;
    const int wave = tid >> 6, lane = tid & 63;
    const int f0 = 2 * lane;
    const int j2 = lane & 31;
    const int kb = (lane >> 5) * 64;

    for (int i = tid; i < 256 * 128; i += 256)
        W1s[i >> 7][i & 127] = f2bf(W1[i]);
    __syncthreads();

    float w1c0[16], w1c1[16];
    #pragma unroll
    for (int k = 0; k < 16; ++k) {
        w1c0[k] = W1[(256 + k) * 128 + f0];
        w1c1[k] = W1[(256 + k) * 128 + f0 + 1];
    }
    float w2r[64];
    #pragma unroll
    for (int kk = 0; kk < 64; ++kk)
        w2r[kk] = W2[(kb + kk) * 32 + j2];
    const float b10 = b1[f0], b11 = b1[f0 + 1];
    const float b2vv = b2[j2], w3vv = W3[j2], b3v = b3[0];

    const long twoE = 2L * E;
    for (long e = (long)blockIdx.x * 4 + wave; e < twoE; e += (long)gridDim.x * 4) {
        const bool rv = (e >= E);
        const int ee = (int)(rv ? e - E : e);
        const int s = (rv ? src_rev : src_orders)[ee];
        const int d = (rv ? dst_rev : dst_orders)[ee];
        const float* hs = rv ? h_item : h_user;
        const float* hd = rv ? h_user : h_item;
        const float* efp = rv ? ef_rev : ef_orders;

        xbuf[wave][lane]       = hs[(size_t)s * 128 + lane];
        xbuf[wave][64 + lane]  = hs[(size_t)s * 128 + 64 + lane];
        xbuf[wave][128 + lane] = hd[(size_t)d * 128 + lane];
        xbuf[wave][192 + lane] = hd[(size_t)d * 128 + 64 + lane];
        __builtin_amdgcn_wave_barrier();

        float p0 = b10, p1 = b11;
        #pragma unroll 8
        for (int k = 0; k < 256; ++k) {
            float xv = xbuf[wave][k];
            unsigned int w = *(const unsigned int*)&W1s[k][f0];
            p0 = fmaf(xv, bf2f_lo(w), p0);
            p1 = fmaf(xv, bf2f_hi(w), p1);
        }
        const float efv = efp[(size_t)ee * 16 + (lane & 15)];
        #pragma unroll
        for (int k = 0; k < 16; ++k) {
            float ek = __shfl(efv, k, 64);
            p0 = fmaf(ek, w1c0[k], p0);
            p1 = fmaf(ek, w1c1[k], p1);
        }
        p0 = fmaxf(p0, 0.0f);
        p1 = fmaxf(p1, 0.0f);

        *(float2*)&h1s[wave][f0] = make_float2(p0, p1);
        __builtin_amdgcn_wave_barrier();
        float acc = 0.0f;
        #pragma unroll
        for (int q = 0; q < 16; ++q) {
            float4 hv = *(const float4*)&h1s[wave][kb + q * 4];
            acc = fmaf(hv.x, w2r[4 * q + 0], acc);
            acc = fmaf(hv.y, w2r[4 * q + 1], acc);
            acc = fmaf(hv.z, w2r[4 * q + 2], acc);
            acc = fmaf(hv.w, w2r[4 * q + 3], acc);
        }
        __builtin_amdgcn_wave_barrier();
        acc += __shfl_xor(acc, 32, 64);
        float h2 = fmaxf(acc + b2vv, 0.0f);
        float v = h2 * w3vv;
        v += __shfl_xor(v, 16, 64);
        v += __shfl_xor(v, 8, 64);
        v += __shfl_xor(v, 4, 64);
        v += __shfl_xor(v, 2, 64);
        v += __shfl_xor(v, 1, 64);
        if (lane == 0)
            out[e] = 1.0f / (1.0f + __expf(-(v + b3v)));
    }
}

// ---------------------------------------------------------------------------
extern "C" void kernel_launch(void* const* d_in, const int* in_sizes, int n_in,
                              void* d_out, int out_size, void* d_ws, size_t ws_size,
                              hipStream_t stream)
{
    const float* h_user    = (const float*)d_in[0];
    const float* h_item    = (const float*)d_in[1];
    const float* ef_orders = (const float*)d_in[2];
    const float* ef_rev    = (const float*)d_in[3];
    const float* W1        = (const float*)d_in[4];
    const float* b1        = (const float*)d_in[5];
    const float* W2        = (const float*)d_in[6];
    const float* b2        = (const float*)d_in[7];
    const float* W3        = (const float*)d_in[8];
    const float* b3        = (const float*)d_in[9];
    const int* src_orders  = (const int*)d_in[10];
    const int* dst_orders  = (const int*)d_in[11];
    const int* src_rev     = (const int*)d_in[12];
    const int* dst_rev     = (const int*)d_in[13];

    const int n_user = in_sizes[0] / 128;
    const int n_item = in_sizes[1] / 128;
    const int E      = in_sizes[2] / 16;
    float* out = (float*)d_out;

    const size_t need = (size_t)(n_user + n_item) * 256;  // fp8: 1 B/elem
    if (ws_size >= need) {
        unsigned char* Yu = (unsigned char*)d_ws;
        unsigned char* Yi = Yu + (size_t)n_user * 256;
        precompute_mfma<<<2048, 256, 0, stream>>>(h_user, n_user, h_item, n_item, W1, Yu, Yi);
        edge_mfma<<<1024, 256, 0, stream>>>(Yu, Yi, ef_orders, ef_rev,
            src_orders, dst_orders, src_rev, dst_rev,
            W1, b1, W2, b2, W3, b3, out, E);
    } else {
        edge_mlp_direct<<<4096, 256, 0, stream>>>(h_user, h_item, ef_orders, ef_rev,
            src_orders, dst_orders, src_rev, dst_rev,
            W1, b1, W2, b2, W3, b3, out, E);
    }
}

// Round 10
// 104.486 us; speedup vs baseline: 2.0405x; 1.0810x over previous
//
#include <hip/hip_runtime.h>
#include <hip/hip_bf16.h>

typedef __attribute__((ext_vector_type(8))) short bfrag;   // 8 bf16 (A/B operand)
typedef __attribute__((ext_vector_type(4))) float facc;    // 4 f32  (C/D operand)
typedef __attribute__((ext_vector_type(2))) float f32x2;

static __device__ __forceinline__ float bf2f_lo(unsigned int u) {
    return __uint_as_float(u << 16);
}
static __device__ __forceinline__ float bf2f_hi(unsigned int u) {
    return __uint_as_float(u & 0xffff0000u);
}
static __device__ __forceinline__ unsigned short f2bf(float f) {
    __hip_bfloat16 b = __float2bfloat16(f);  // RNE
    return *reinterpret_cast<unsigned short*>(&b);
}

// ---------------------------------------------------------------------------
// Precompute: Y[row][0:256] = h[row] @ [W1a | W1b], fp8-e4m3.
//  - h tile staged once per block in padded LDS (f32 [16][132]), coalesced
//  - A = W1 frags (loop-invariant registers), B = h from LDS
//  - round-10: Y stores repacked through per-wave LDS so 4 lanes emit one
//    FULL 64B line per instruction (1 store instr/wave/tile, was 4 instrs
//    writing 16B sectors -> 4x the L2 line-touches; store-side touches were
//    ~2.4M vs the h-read's 1.2M against the ~70G touch/s wall)
// ---------------------------------------------------------------------------
extern "C" __global__ __launch_bounds__(256)
void precompute_mfma(const float* __restrict__ hu, int nu,
                     const float* __restrict__ hi, int ni,
                     const float* __restrict__ W1,
                     unsigned char* __restrict__ Yu,
                     unsigned char* __restrict__ Yi)
{
    __shared__ __align__(16) float hstage[2][16][132];
    __shared__ __align__(16) unsigned int repack[4][16][20];  // [wave][node][nt*4+g], 20-dw pad
    const int tid = threadIdx.x, wave = tid >> 6, lane = tid & 63;
    const int g = lane >> 4, e16 = lane & 15;
    const int c0 = wave * 64;

    // A-frags: W1 columns j = c0 + nt*16 + e16 (m = e16), k = kk*32 + g*8 + i
    bfrag aw1[4][4];
    #pragma unroll
    for (int nt = 0; nt < 4; ++nt) {
        const int j = c0 + nt * 16 + e16;
        #pragma unroll
        for (int kk = 0; kk < 4; ++kk) {
            bfrag v;
            #pragma unroll
            for (int i = 0; i < 8; ++i) {
                int k = kk * 32 + g * 8 + i;
                float w = (j < 128) ? W1[(size_t)k * 128 + j]
                                    : W1[(size_t)(128 + k) * 128 + (j - 128)];
                v[i] = (short)f2bf(w);
            }
            aw1[nt][kk] = v;
        }
    }

    const int srow = tid >> 5;          // 0..7
    const int scol = (tid & 31) * 4;    // 0..124

    const int tu = (nu + 15) >> 4, ti = (ni + 15) >> 4, tt = tu + ti;
    const int stride = gridDim.x;
    int tile = blockIdx.x;

    const float* hs_c = hu; unsigned char* Y_c = Yu; int n_c = nu, node0_c = 0;
    const float* hs_n; unsigned char* Y_n; int n_n, node0_n;
    float4 sA, sB;

#define SETSRC(T, HS, YP, NN, N0) do {                                        \
        if ((T) < tu) { HS = hu; YP = Yu; NN = nu; N0 = (T) * 16; }           \
        else          { HS = hi; YP = Yi; NN = ni; N0 = ((T) - tu) * 16; }    \
    } while (0)

#define LOADTILE(HS, NN, N0) do {                                             \
        int rA_ = (N0) + srow;     if (rA_ >= (NN)) rA_ = (NN) - 1;           \
        int rB_ = (N0) + 8 + srow; if (rB_ >= (NN)) rB_ = (NN) - 1;           \
        sA = *(const float4*)((HS) + (size_t)rA_ * 128 + scol);               \
        sB = *(const float4*)((HS) + (size_t)rB_ * 128 + scol);               \
    } while (0)

#define STAGE(BUF) do {                                                       \
        *(float4*)&hstage[BUF][srow][scol]     = sA;                          \
        *(float4*)&hstage[BUF][8 + srow][scol] = sB;                          \
    } while (0)

    if (tile < tt) {
        SETSRC(tile, hs_c, Y_c, n_c, node0_c);
        LOADTILE(hs_c, n_c, node0_c);
        STAGE(0);
    }
    __syncthreads();
    int buf = 0;

    for (; tile < tt; tile += stride) {
        const int tn = tile + stride;
        if (tn < tt) {
            SETSRC(tn, hs_n, Y_n, n_n, node0_n);
            LOADTILE(hs_n, n_n, node0_n);   // in flight across compute
        }

        // compute: B-frags from LDS (2x ds_read_b128 per kk), 16 MFMA
        facc acc[4] = {{0,0,0,0},{0,0,0,0},{0,0,0,0},{0,0,0,0}};
        #pragma unroll
        for (int kk = 0; kk < 4; ++kk) {
            const float4 b0 = *(const float4*)&hstage[buf][e16][kk * 32 + g * 8];
            const float4 b1 = *(const float4*)&hstage[buf][e16][kk * 32 + g * 8 + 4];
            bfrag bf;
            bf[0] = (short)f2bf(b0.x); bf[1] = (short)f2bf(b0.y);
            bf[2] = (short)f2bf(b0.z); bf[3] = (short)f2bf(b0.w);
            bf[4] = (short)f2bf(b1.x); bf[5] = (short)f2bf(b1.y);
            bf[6] = (short)f2bf(b1.z); bf[7] = (short)f2bf(b1.w);
            #pragma unroll
            for (int nt = 0; nt < 4; ++nt)
                acc[nt] = __builtin_amdgcn_mfma_f32_16x16x32_bf16(aw1[nt][kk], bf, acc[nt], 0, 0, 0);
        }

        // pack fp8 quads into per-wave LDS: repack[e16][nt*4+g] = 4 bytes
        // (j = c0+nt*16+g*4 .. +3 of node e16)
        #pragma unroll
        for (int nt = 0; nt < 4; ++nt) {
            unsigned int pk = __builtin_amdgcn_cvt_pk_fp8_f32(acc[nt][0], acc[nt][1], 0u, false);
            pk = __builtin_amdgcn_cvt_pk_fp8_f32(acc[nt][2], acc[nt][3], pk, true);
            repack[wave][e16][nt * 4 + g] = pk;
        }
        __builtin_amdgcn_wave_barrier();   // wave-synchronous DS; fence compiler

        // full-line store: lane (node=l>>2, q=l&3) emits 16B; 4 lanes = 64B line
        {
            const int nd = lane >> 2, q = lane & 3;
            uint4 v = *(const uint4*)&repack[wave][nd][q * 4];
            const int nodeg = node0_c + nd;
            if (nodeg < n_c)
                *(uint4*)&Y_c[(size_t)nodeg * 256 + c0 + q * 16] = v;
        }
        __builtin_amdgcn_wave_barrier();

        if (tn < tt) {
            __syncthreads();            // all waves done reading both buffers
            STAGE(buf ^ 1);             // vmcnt wait on sA/sB lands here
            __syncthreads();
            hs_c = hs_n; Y_c = Y_n; n_c = n_n; node0_c = node0_n;
        }
        buf ^= 1;
    }
#undef SETSRC
#undef LOADTILE
#undef STAGE
}

// ---------------------------------------------------------------------------
// Edge phase (unchanged from round 8/9, at the line-request floor):
// 16 edges/wave, edges-as-columns MFMA, contiguous 16B per-lane chunks
// coalescing to one 64B line-request per edge-line; fp8 Y; software-pipelined.
// ---------------------------------------------------------------------------
extern "C" __global__ __launch_bounds__(256, 3)
void edge_mfma(const unsigned char* __restrict__ Yu,
               const unsigned char* __restrict__ Yi,
               const float* __restrict__ ef_orders,
               const float* __restrict__ ef_rev,
               const int* __restrict__ src_orders,
               const int* __restrict__ dst_orders,
               const int* __restrict__ src_rev,
               const int* __restrict__ dst_rev,
               const float* __restrict__ W1,
               const float* __restrict__ b1,
               const float* __restrict__ W2,
               const float* __restrict__ b2,
               const float* __restrict__ W3,
               const float* __restrict__ b3,
               float* __restrict__ out, int E)
{
    __shared__ __align__(16) unsigned short d1_lds[4][16][128];  // 16 KB
    const int tid = threadIdx.x, wave = tid >> 6, lane = tid & 63;
    const int g = lane >> 4, e16 = lane & 15;
    unsigned short (*my_lds)[128] = d1_lds[wave];
    const int swzb = (e16 & 7) << 3;   // bf16-unit XOR, 16B granule

    // A frags for ef GEMM, spread mapping: k-slot (g, i<4) <-> ef[4g+i];
    // slot (g==0, i==4) carries b1 (B supplies 1.0 there); all else zero.
    bfrag a1[8];
    #pragma unroll
    for (int t = 0; t < 8; ++t) {
        bfrag v;
        #pragma unroll
        for (int i = 0; i < 8; ++i) {
            unsigned short s16 = 0;
            if (i < 4)                s16 = f2bf(W1[(size_t)(256 + 4 * g + i) * 128 + t * 16 + e16]);
            else if (i == 4 && g == 0) s16 = f2bf(b1[t * 16 + e16]);
            v[i] = (short)s16;
        }
        a1[t] = v;
    }
    // W2^T A-frags with the gather permutation:
    // slot (kk,g,i) <-> k = (kk>>1)*64 + 16g + (kk&1)*8 + i
    bfrag w2t[2][4];
    #pragma unroll
    for (int nt = 0; nt < 2; ++nt)
        #pragma unroll
        for (int kk = 0; kk < 4; ++kk) {
            bfrag v;
            #pragma unroll
            for (int i = 0; i < 8; ++i) {
                int k = (kk >> 1) * 64 + 16 * g + (kk & 1) * 8 + i;
                v[i] = (short)f2bf(W2[(size_t)k * 32 + nt * 16 + e16]);
            }
            w2t[nt][kk] = v;
        }
    float b2v[2][4], w3v[2][4];
    #pragma unroll
    for (int nt = 0; nt < 2; ++nt)
        #pragma unroll
        for (int r = 0; r < 4; ++r) {
            b2v[nt][r] = b2[nt * 16 + g * 4 + r];
            w3v[nt][r] = W3[nt * 16 + g * 4 + r];
        }
    const float b3s = b3[0];

    const long twoE = 2L * E;
    const int nbatch = (int)((twoE + 15) >> 4);
    const int stride = gridDim.x * 4;
    int b = blockIdx.x * 4 + wave;

    // pipeline state — all named scalars/vectors (register-resident)
    int s_pf = 0, d_pf = 0;
    uint4 ysA, ysB, ydA, ydB;
    float4 efq = make_float4(0, 0, 0, 0);

#define LOADIDX(BB) do {                                                      \
        long el_ = ((long)(BB) << 4) + e16;                                   \
        if (el_ >= twoE) el_ = twoE - 1;                                      \
        const bool rv_ = el_ >= E;                                            \
        const int ee_ = (int)(rv_ ? el_ - E : el_);                           \
        s_pf = (rv_ ? src_rev : src_orders)[ee_];                             \
        d_pf = (rv_ ? dst_rev : dst_orders)[ee_];                             \
    } while (0)

#define GATHER(BB) do {                                                       \
        long el_ = ((long)(BB) << 4) + e16;                                   \
        if (el_ >= twoE) el_ = twoE - 1;                                      \
        const bool rv_ = el_ >= E;                                            \
        const int ee_ = (int)(rv_ ? el_ - E : el_);                           \
        const unsigned char* ps_ = (rv_ ? Yi : Yu) + (size_t)s_pf * 256 + g * 16; \
        const unsigned char* pd_ = (rv_ ? Yu : Yi) + (size_t)d_pf * 256 + 128 + g * 16; \
        ysA = *(const uint4*)(ps_);       ysB = *(const uint4*)(ps_ + 64);    \
        ydA = *(const uint4*)(pd_);       ydB = *(const uint4*)(pd_ + 64);    \
        efq = *(const float4*)((rv_ ? ef_rev : ef_orders) + (size_t)ee_ * 16 + g * 4); \
    } while (0)

#define PSTEP(KK, YSL, YSH, YDL, YDH) do {                                    \
        const int dlo_ = (((KK) >> 1) * 64 + 16 * g + ((KK) & 1) * 8) ^ swzb; \
        uint4 wv = *(const uint4*)&my_lds[e16][dlo_];                         \
        f32x2 s01 = __builtin_amdgcn_cvt_pk_f32_fp8(YSL, false);              \
        f32x2 s23 = __builtin_amdgcn_cvt_pk_f32_fp8(YSL, true);               \
        f32x2 s45 = __builtin_amdgcn_cvt_pk_f32_fp8(YSH, false);              \
        f32x2 s67 = __builtin_amdgcn_cvt_pk_f32_fp8(YSH, true);               \
        f32x2 d01 = __builtin_amdgcn_cvt_pk_f32_fp8(YDL, false);              \
        f32x2 d23 = __builtin_amdgcn_cvt_pk_f32_fp8(YDL, true);               \
        f32x2 d45 = __builtin_amdgcn_cvt_pk_f32_fp8(YDH, false);              \
        f32x2 d67 = __builtin_amdgcn_cvt_pk_f32_fp8(YDH, true);               \
        float p0 = s01[0] + d01[0] + bf2f_lo(wv.x);                           \
        float p1 = s01[1] + d01[1] + bf2f_hi(wv.x);                           \
        float p2 = s23[0] + d23[0] + bf2f_lo(wv.y);                           \
        float p3 = s23[1] + d23[1] + bf2f_hi(wv.y);                           \
        float p4 = s45[0] + d45[0] + bf2f_lo(wv.z);                           \
        float p5 = s45[1] + d45[1] + bf2f_hi(wv.z);                           \
        float p6 = s67[0] + d67[0] + bf2f_lo(wv.w);                           \
        float p7 = s67[1] + d67[1] + bf2f_hi(wv.w);                           \
        bfrag pa;                                                             \
        pa[0] = (short)f2bf(fmaxf(p0, 0.f)); pa[1] = (short)f2bf(fmaxf(p1, 0.f)); \
        pa[2] = (short)f2bf(fmaxf(p2, 0.f)); pa[3] = (short)f2bf(fmaxf(p3, 0.f)); \
        pa[4] = (short)f2bf(fmaxf(p4, 0.f)); pa[5] = (short)f2bf(fmaxf(p5, 0.f)); \
        pa[6] = (short)f2bf(fmaxf(p6, 0.f)); pa[7] = (short)f2bf(fmaxf(p7, 0.f)); \
        acc2a = __builtin_amdgcn_mfma_f32_16x16x32_bf16(w2t[0][KK], pa, acc2a, 0, 0, 0); \
        acc2b = __builtin_amdgcn_mfma_f32_16x16x32_bf16(w2t[1][KK], pa, acc2b, 0, 0, 0); \
    } while (0)

    if (b < nbatch) {
        LOADIDX(b);
        GATHER(b);
        if (b + stride < nbatch) LOADIDX(b + stride);
    }

    for (; b < nbatch; b += stride) {
        // B frag from prefetched ef: slots i<4 = ef[4g+i]; (g0,i4) = 1.0
        bfrag eb;
        #pragma unroll
        for (int i = 0; i < 8; ++i) eb[i] = 0;
        eb[0] = (short)f2bf(efq.x); eb[1] = (short)f2bf(efq.y);
        eb[2] = (short)f2bf(efq.z); eb[3] = (short)f2bf(efq.w);
        if (g == 0) eb[4] = (short)0x3F80;  // bf16 1.0 -> adds b1[n]

        // D1 = W1c^T @ ef^T + b1 -> bf16 LDS transpose (swizzled)
        #pragma unroll
        for (int t = 0; t < 8; ++t) {
            facc zero = {0, 0, 0, 0};
            facc d1 = __builtin_amdgcn_mfma_f32_16x16x32_bf16(a1[t], eb, zero, 0, 0, 0);
            ushort4 u;
            u.x = f2bf(d1[0]); u.y = f2bf(d1[1]); u.z = f2bf(d1[2]); u.w = f2bf(d1[3]);
            *(ushort4*)&my_lds[e16][(t * 16 + g * 4) ^ swzb] = u;
        }

        // P build + second GEMM (consumes prefetched ys/yd registers)
        facc acc2a = {0, 0, 0, 0}, acc2b = {0, 0, 0, 0};
        PSTEP(0, ysA.x, ysA.y, ydA.x, ydA.y);
        PSTEP(1, ysA.z, ysA.w, ydA.z, ydA.w);
        PSTEP(2, ysB.x, ysB.y, ydB.x, ydB.y);
        PSTEP(3, ysB.z, ysB.w, ydB.z, ydB.w);

        // issue next batch's gathers now that ys/yd are consumed;
        // latency hides under tail + next iter's D1 phase + wave TLP
        const int bn = b + stride;
        if (bn < nbatch) GATHER(bn);

        // tail: relu(h2+b2) . W3, reduce over g-groups, sigmoid, store
        float h3 = 0.f;
        #pragma unroll
        for (int r = 0; r < 4; ++r) {
            float h2 = fmaxf(acc2a[r] + b2v[0][r], 0.f);
            h3 = fmaf(h2, w3v[0][r], h3);
        }
        #pragma unroll
        for (int r = 0; r < 4; ++r) {
            float h2 = fmaxf(acc2b[r] + b2v[1][r], 0.f);
            h3 = fmaf(h2, w3v[1][r], h3);
        }
        h3 += __shfl_xor(h3, 16, 64);
        h3 += __shfl_xor(h3, 32, 64);
        const long el = ((long)b << 4) + lane;
        if (lane < 16 && el < twoE)
            out[el] = 1.f / (1.f + __expf(-(h3 + b3s)));

        // indices for b + 2*stride (consumed by next iteration's GATHER)
        const int b2n = b + 2 * stride;
        if (b2n < nbatch) LOADIDX(b2n);
    }
#undef LOADIDX
#undef GATHER
#undef PSTEP
}

// ---------------------------------------------------------------------------
// Fallback (ws too small): direct per-edge MLP (round-1 kernel, known good).
// ---------------------------------------------------------------------------
extern "C" __global__ __launch_bounds__(256)
void edge_mlp_direct(const float* __restrict__ h_user,
                     const float* __restrict__ h_item,
                     const float* __restrict__ ef_orders,
                     const float* __restrict__ ef_rev,
                     const int* __restrict__ src_orders,
                     const int* __restrict__ dst_orders,
                     const int* __restrict__ src_rev,
                     const int* __restrict__ dst_rev,
                     const float* __restrict__ W1,
                     const float* __restrict__ b1,
                     const float* __restrict__ W2,
                     const float* __restrict__ b2,
                     const float* __restrict__ W3,
                     const float* __restrict__ b3,
                     float* __restrict__ out, int E)
{
    __shared__ unsigned short W1s[256][128];
    __shared__ float xbuf[4][256];
    __shared__ float h1s[4][128];
    const int tid = threadIdx.x;
    const int wave = tid >> 6, lane = tid & 63;
    const int f0 = 2 * lane;
    const int j2 = lane & 31;
    const int kb = (lane >> 5) * 64;

    for (int i = tid; i < 256 * 128; i += 256)
        W1s[i >> 7][i & 127] = f2bf(W1[i]);
    __syncthreads();

    float w1c0[16], w1c1[16];
    #pragma unroll
    for (int k = 0; k < 16; ++k) {
        w1c0[k] = W1[(256 + k) * 128 + f0];
        w1c1[k] = W1[(256 + k) * 128 + f0 + 1];
    }
    float w2r[64];
    #pragma unroll
    for (int kk = 0; kk < 64; ++kk)
        w2r[kk] = W2[(kb + kk) * 32 + j2];
    const float b10 = b1[f0], b11 = b1[f0 + 1];
    const float b2vv = b2[j2], w3vv = W3[j2], b3v = b3[0];

    const long twoE = 2L * E;
    for (long e = (long)blockIdx.x * 4 + wave; e < twoE; e += (long)gridDim.x * 4) {
        const bool rv = (e >= E);
        const int ee = (int)(rv ? e - E : e);
        const int s = (rv ? src_rev : src_orders)[ee];
        const int d = (rv ? dst_rev : dst_orders)[ee];
        const float* hs = rv ? h_item : h_user;
        const float* hd = rv ? h_user : h_item;
        const float* efp = rv ? ef_rev : ef_orders;

        xbuf[wave][lane]       = hs[(size_t)s * 128 + lane];
        xbuf[wave][64 + lane]  = hs[(size_t)s * 128 + 64 + lane];
        xbuf[wave][128 + lane] = hd[(size_t)d * 128 + lane];
        xbuf[wave][192 + lane] = hd[(size_t)d * 128 + 64 + lane];
        __builtin_amdgcn_wave_barrier();

        float p0 = b10, p1 = b11;
        #pragma unroll 8
        for (int k = 0; k < 256; ++k) {
            float xv = xbuf[wave][k];
            unsigned int w = *(const unsigned int*)&W1s[k][f0];
            p0 = fmaf(xv, bf2f_lo(w), p0);
            p1 = fmaf(xv, bf2f_hi(w), p1);
        }
        const float efv = efp[(size_t)ee * 16 + (lane & 15)];
        #pragma unroll
        for (int k = 0; k < 16; ++k) {
            float ek = __shfl(efv, k, 64);
            p0 = fmaf(ek, w1c0[k], p0);
            p1 = fmaf(ek, w1c1[k], p1);
        }
        p0 = fmaxf(p0, 0.0f);
        p1 = fmaxf(p1, 0.0f);

        *(float2*)&h1s[wave][f0] = make_float2(p0, p1);
        __builtin_amdgcn_wave_barrier();
        float acc = 0.0f;
        #pragma unroll
        for (int q = 0; q < 16; ++q) {
            float4 hv = *(const float4*)&h1s[wave][kb + q * 4];
            acc = fmaf(hv.x, w2r[4 * q + 0], acc);
            acc = fmaf(hv.y, w2r[4 * q + 1], acc);
            acc = fmaf(hv.z, w2r[4 * q + 2], acc);
            acc = fmaf(hv.w, w2r[4 * q + 3], acc);
        }
        __builtin_amdgcn_wave_barrier();
        acc += __shfl_xor(acc, 32, 64);
        float h2 = fmaxf(acc + b2vv, 0.0f);
        float v = h2 * w3vv;
        v += __shfl_xor(v, 16, 64);
        v += __shfl_xor(v, 8, 64);
        v += __shfl_xor(v, 4, 64);
        v += __shfl_xor(v, 2, 64);
        v += __shfl_xor(v, 1, 64);
        if (lane == 0)
            out[e] = 1.0f / (1.0f + __expf(-(v + b3v)));
    }
}

// ---------------------------------------------------------------------------
extern "C" void kernel_launch(void* const* d_in, const int* in_sizes, int n_in,
                              void* d_out, int out_size, void* d_ws, size_t ws_size,
                              hipStream_t stream)
{
    const float* h_user    = (const float*)d_in[0];
    const float* h_item    = (const float*)d_in[1];
    const float* ef_orders = (const float*)d_in[2];
    const float* ef_rev    = (const float*)d_in[3];
    const float* W1        = (const float*)d_in[4];
    const float* b1        = (const float*)d_in[5];
    const float* W2        = (const float*)d_in[6];
    const float* b2        = (const float*)d_in[7];
    const float* W3        = (const float*)d_in[8];
    const float* b3        = (const float*)d_in[9];
    const int* src_orders  = (const int*)d_in[10];
    const int* dst_orders  = (const int*)d_in[11];
    const int* src_rev     = (const int*)d_in[12];
    const int* dst_rev     = (const int*)d_in[13];

    const int n_user = in_sizes[0] / 128;
    const int n_item = in_sizes[1] / 128;
    const int E      = in_sizes[2] / 16;
    float* out = (float*)d_out;

    const size_t need = (size_t)(n_user + n_item) * 256;  // fp8: 1 B/elem
    if (ws_size >= need) {
        unsigned char* Yu = (unsigned char*)d_ws;
        unsigned char* Yi = Yu + (size_t)n_user * 256;
        precompute_mfma<<<2048, 256, 0, stream>>>(h_user, n_user, h_item, n_item, W1, Yu, Yi);
        edge_mfma<<<1024, 256, 0, stream>>>(Yu, Yi, ef_orders, ef_rev,
            src_orders, dst_orders, src_rev, dst_rev,
            W1, b1, W2, b2, W3, b3, out, E);
    } else {
        edge_mlp_direct<<<4096, 256, 0, stream>>>(h_user, h_item, ef_orders, ef_rev,
            src_orders, dst_orders, src_rev, dst_rev,
            W1, b1, W2, b2, W3, b3, out, E);
    }
}